// Round 9
// baseline (227.958 us; speedup 1.0000x reference)
//
#include <hip/hip_runtime.h>
#include <hip/hip_bf16.h>
#include <hip/hip_fp8.h>
#include <cmath>

// ---------------------------------------------------------------------------
// Round 24. Base: R23 @ 223.4us (BM=128 head confirmed, -11.8).
//   Residual budget points at the build's low-occupancy kernels (~0.77
//   blocks/CU): bin_prep binning ran 196 blocks (16 serial edges/thread x2
//   passes), csr_fill carried a 64-iter xs0 tail per block.
//   - bin_prep edge-binning now nbin = 4*nbuck = 784 blocks (4x TLP); the
//     gcount run-reservation scheme is block-count-agnostic.
//   - xs0 conversion split out of csr_fill into xs0_prep (1563 blocks,
//     float4x2 -> bf16x8, ~4us BW-bound). csr_fill keeps count/scan/scatter.
//   - (R23) BM=128 head; (R20) slice-owned aggregates; (R17) k-tile-
//     stationary head; (R16) conv12 H1-LDS fusion; (R11) fp8 xw;
//     bf16 MFMA 128x128/BK32 + XOR-swizzled LDS + global_load_lds w16.
// ---------------------------------------------------------------------------

typedef __bf16 bf16;
typedef __bf16 bf16x2 __attribute__((ext_vector_type(2)));
typedef __bf16 bf16x4 __attribute__((ext_vector_type(4)));
typedef __bf16 bf16x8 __attribute__((ext_vector_type(8)));
typedef float  f32x4  __attribute__((ext_vector_type(4)));
typedef unsigned char fp8s;   // e4m3 storage byte

#define BUCKET_CAP 8192       // expected load 4096 (Poisson), overflow ~impossible

__device__ __forceinline__ void load_lds16(const bf16* g, bf16* l) {
    __builtin_amdgcn_global_load_lds(
        (const __attribute__((address_space(1))) void*)g,
        (__attribute__((address_space(3))) void*)l, 16, 0, 0);
}

__device__ __forceinline__ bf16 convert_out(float v, bf16*) { return (bf16)v; }
__device__ __forceinline__ fp8s convert_out(float v, fp8s*) {
    __hip_fp8_e4m3 q(v); return (fp8s)q.__x;
}

__device__ __forceinline__ float4 fp8x4_to_f4(unsigned int p) {
    __hip_fp8x2_e4m3 lo, hi;
    lo.__x = (__hip_fp8x2_storage_t)(p & 0xffffu);
    hi.__x = (__hip_fp8x2_storage_t)(p >> 16);
    float2 a = (float2)lo, c = (float2)hi;
    return make_float4(a.x, a.y, c.x, c.y);
}

// ---------------- CSR build (fixed-capacity buckets, N <= 65536) ----------------

// blocks [0,nbin): bin edges by dst>>8 into pairs[b*CAP ..] — per-block LDS
// hist, one global atomicAdd per touched bucket reserves a run (block-count-
// agnostic). blocks [nbin, nbin+736): weight transpose/cast.
__launch_bounds__(256)
__global__ void bin_prep(const int* __restrict__ src, const int* __restrict__ dst,
                         int* __restrict__ gcount, unsigned int* __restrict__ pairs,
                         int e, int nbin,
                         const float* __restrict__ W1, const float* __restrict__ W2,
                         const float* __restrict__ W3, const float* __restrict__ lW1,
                         bf16* __restrict__ Wt1, bf16* __restrict__ Wt2,
                         bf16* __restrict__ Wt3, bf16* __restrict__ lW1_bf) {
    int t = threadIdx.x;
    if ((int)blockIdx.x >= nbin) {
        int i = (blockIdx.x - nbin) * 256 + t;
        if (i < 8192) {
            int k = i >> 7, c = i & 127; Wt1[c * 64 + k] = (bf16)W1[i];
        } else if (i < 24576) {
            int j = i - 8192; int k = j >> 7, c = j & 127; Wt2[c * 128 + k] = (bf16)W2[j];
        } else if (i < 40960) {
            int j = i - 24576; int k = j >> 7, c = j & 127; Wt3[c * 128 + k] = (bf16)W3[j];
        } else if (i < 188416) {
            int j = i - 40960; lW1_bf[j] = (bf16)lW1[j];
        }
        return;
    }
    __shared__ int hist[256], base[256], cur[256];
    hist[t] = 0; cur[t] = 0;
    __syncthreads();
    int perBlock = (e + nbin - 1) / nbin;
    int lo = blockIdx.x * perBlock;
    int hi = lo + perBlock; if (hi > e) hi = e;
    for (int i = lo + t; i < hi; i += 256)
        atomicAdd(&hist[dst[i] >> 8], 1);
    __syncthreads();
    if (hist[t] > 0) base[t] = atomicAdd(&gcount[t], hist[t]);
    __syncthreads();
    for (int i = lo + t; i < hi; i += 256) {
        int d = dst[i];
        int b = d >> 8;
        int r = base[b] + atomicAdd(&cur[b], 1);
        if (r < BUCKET_CAP)   // overflow guard (statistically impossible)
            pairs[(size_t)b * BUCKET_CAP + r] = (unsigned)src[i] | ((unsigned)(d & 255) << 16);
    }
}

// one block per bucket (region [b*CAP, b*CAP+gcount[b])): per-node counts ->
// rpS/rpE + dinv; LDS-window scatter -> coalesced col.
#define FILL_CAP 6144
__launch_bounds__(256)
__global__ void csr_fill_full(const unsigned int* __restrict__ pairs,
                              const int* __restrict__ gcount,
                              int* __restrict__ rpS, int* __restrict__ rpE,
                              float* __restrict__ dinv,
                              int* __restrict__ col, int n) {
    __shared__ int cnt[256];
    __shared__ int ofs[256];
    __shared__ int ss[256];
    __shared__ int win[FILL_CAP];
    int b = blockIdx.x, t = threadIdx.x;
    int nodeBase = b << 8;
    int lo = b * BUCKET_CAP;
    int bcountE = gcount[b]; if (bcountE > BUCKET_CAP) bcountE = BUCKET_CAP;
    cnt[t] = 0;
    __syncthreads();
    for (int i = t; i < bcountE; i += 256)
        atomicAdd(&cnt[pairs[lo + i] >> 16], 1);
    __syncthreads();
    int myc = cnt[t];
    ss[t] = myc;
    __syncthreads();
#pragma unroll
    for (int off = 1; off < 256; off <<= 1) {
        int tmp = (t >= off) ? ss[t - off] : 0;
        __syncthreads();
        ss[t] += tmp;
        __syncthreads();
    }
    int excl = ss[t] - myc;
    ofs[t] = excl;
    int node = nodeBase + t;
    if (node < n) {
        rpS[node] = lo + excl;
        rpE[node] = lo + excl + myc;
        dinv[node] = rsqrtf((float)(myc + 1));   // +1 self-loop
    }
    cnt[t] = 0;
    __syncthreads();
    if (bcountE <= FILL_CAP) {
        for (int i = t; i < bcountE; i += 256) {
            unsigned p = pairs[lo + i];
            int dl = (int)(p >> 16);
            int r = atomicAdd(&cnt[dl], 1);
            win[ofs[dl] + r] = (int)(p & 0xffffu);
        }
        __syncthreads();
        for (int i = t; i < bcountE; i += 256) col[lo + i] = win[i];
    } else {
        for (int i = t; i < bcountE; i += 256) {
            unsigned p = pairs[lo + i];
            int dl = (int)(p >> 16);
            int r = atomicAdd(&cnt[dl], 1);
            col[lo + ofs[dl] + r] = (int)(p & 0xffffu);
        }
    }
}

// xs0 = bf16(dinv[row] * x[row]) — full-TLP BW kernel (8 threads/row).
__launch_bounds__(256)
__global__ void xs0_prep(const float* __restrict__ x, const float* __restrict__ dinv,
                         bf16* __restrict__ xs0, int n) {
    int tid = blockIdx.x * 256 + threadIdx.x;   // n*8 total
    if (tid >= n * 8) return;
    float d = dinv[tid >> 3];
    const float4* xp = (const float4*)(x + (size_t)tid * 8);
    float4 a = xp[0], b = xp[1];
    bf16x8 o;
    o[0] = (bf16)(a.x * d); o[1] = (bf16)(a.y * d);
    o[2] = (bf16)(a.z * d); o[3] = (bf16)(a.w * d);
    o[4] = (bf16)(b.x * d); o[5] = (bf16)(b.y * d);
    o[6] = (bf16)(b.z * d); o[7] = (bf16)(b.w * d);
    *(bf16x8*)(xs0 + (size_t)tid * 8) = o;
}

// -------- fallback CSR build for N > 65536 (not used at this size) --------

__launch_bounds__(256)
__global__ void init_kernel(int* __restrict__ cnt, int* __restrict__ fill, int n) {
    int i = blockIdx.x * 256 + threadIdx.x;
    if (i < n) { cnt[i] = 1; fill[i] = 0; }
}

__launch_bounds__(256)
__global__ void hist_kernel(const int* __restrict__ dst, int* __restrict__ cnt, int e) {
    int i = blockIdx.x * 256 + threadIdx.x;
    if (i < e) atomicAdd(&cnt[dst[i]], 1);
}

__launch_bounds__(256)
__global__ void block_reduce(const int* __restrict__ cnt, int* __restrict__ bsum, int n) {
    __shared__ int s[256];
    int t = threadIdx.x;
    int i = blockIdx.x * 256 + t;
    int v = (i < n) ? cnt[i] - 1 : 0;
    s[t] = v;
    __syncthreads();
#pragma unroll
    for (int off = 128; off > 0; off >>= 1) {
        if (t < off) s[t] += s[t + off];
        __syncthreads();
    }
    if (t == 0) bsum[blockIdx.x] = s[0];
}

__launch_bounds__(256)
__global__ void scan_bsums(int* __restrict__ bsum, int nb) {
    __shared__ int s[256];
    int t = threadIdx.x;
    int v = (t < nb) ? bsum[t] : 0;
    s[t] = v;
    __syncthreads();
#pragma unroll
    for (int off = 1; off < 256; off <<= 1) {
        int tmp = (t >= off) ? s[t - off] : 0;
        __syncthreads();
        s[t] += tmp;
        __syncthreads();
    }
    if (t < nb) bsum[t] = s[t] - v;
}

__launch_bounds__(256)
__global__ void write_rp_fb(const int* __restrict__ cnt, const int* __restrict__ bsum,
                            const float* __restrict__ x,
                            int* __restrict__ rpS, int* __restrict__ rpE,
                            float* __restrict__ dinv,
                            bf16* __restrict__ xs0, int n) {
    __shared__ int s[256];
    int t = threadIdx.x;
    int i = blockIdx.x * 256 + t;
    int c = (i < n) ? cnt[i] : 1;
    int v = c - 1;
    s[t] = v;
    __syncthreads();
#pragma unroll
    for (int off = 1; off < 256; off <<= 1) {
        int tmp = (t >= off) ? s[t - off] : 0;
        __syncthreads();
        s[t] += tmp;
        __syncthreads();
    }
    if (i < n) {
        int start = bsum[blockIdx.x] + s[t] - v;
        rpS[i] = start;
        rpE[i] = start + v;
        float d = rsqrtf((float)c);
        dinv[i] = d;
        for (int k = 0; k < 64; ++k)
            xs0[(size_t)i * 64 + k] = (bf16)(x[(size_t)i * 64 + k] * d);
    }
}

__launch_bounds__(256)
__global__ void fill_kernel(const int* __restrict__ src, const int* __restrict__ dst,
                            const int* __restrict__ rpS, int* __restrict__ fill,
                            int* __restrict__ col, int e) {
    int i = blockIdx.x * 256 + threadIdx.x;
    if (i < e) {
        int d = dst[i];
        int pos = rpS[d] + atomicAdd(&fill[d], 1);
        col[pos] = src[i];
    }
}

// ---------------- MFMA GEMM (generic, EPI: 0 = rowScale, 1 = +bias) ----------------
template<int EPI, typename OutT>
__launch_bounds__(256, 4)
__global__ void mfma_gemm(const bf16* __restrict__ A, int strideA, int K,
                          const bf16* __restrict__ Bt,
                          const float* __restrict__ bias,
                          const float* __restrict__ rowScale,
                          OutT* __restrict__ C, int strideC, int n) {
    __shared__ bf16 As[128 * 32];
    __shared__ bf16 Bs[128 * 32];
    int t = threadIdx.x;
    int rowBase = blockIdx.x * 128;
    int colBase = blockIdx.y * 128;

    int lane = t & 63;
    int wv   = t >> 6;
    int wr   = wv >> 1, wc = wv & 1;
    int ml   = lane & 15, quad = lane >> 4;

    f32x4 acc[4][4];
#pragma unroll
    for (int i = 0; i < 4; ++i)
#pragma unroll
        for (int j = 0; j < 4; ++j) acc[i][j] = (f32x4){0.f, 0.f, 0.f, 0.f};

    int srow0 = wv * 32 + (lane >> 2);
    int cchunk = lane & 3;

    for (int kt = 0; kt < K; kt += 32) {
        __syncthreads();
#pragma unroll
        for (int inst = 0; inst < 2; ++inst) {
            int r  = srow0 + inst * 16;
            int gc = (cchunk ^ (r & 3)) * 8;
            int gr = rowBase + r; if (gr >= n) gr = n - 1;
            load_lds16(A + (size_t)gr * strideA + kt + gc,
                       &As[(wv * 128 + inst * 64) * 8]);
            int br = colBase + r;
            load_lds16(Bt + (size_t)br * K + kt + gc,
                       &Bs[(wv * 128 + inst * 64) * 8]);
        }
        __syncthreads();
        bf16x8 af[4], bfv[4];
#pragma unroll
        for (int i = 0; i < 4; ++i) {
            int ra = wr * 64 + i * 16 + ml;
            int rb = wc * 64 + i * 16 + ml;
            af[i]  = *(const bf16x8*)&As[(ra * 4 + (quad ^ (ra & 3))) * 8];
            bfv[i] = *(const bf16x8*)&Bs[(rb * 4 + (quad ^ (rb & 3))) * 8];
        }
#pragma unroll
        for (int i = 0; i < 4; ++i)
#pragma unroll
            for (int j = 0; j < 4; ++j)
                acc[i][j] = __builtin_amdgcn_mfma_f32_16x16x32_bf16(
                    af[i], bfv[j], acc[i][j], 0, 0, 0);
    }

#pragma unroll
    for (int i = 0; i < 4; ++i) {
#pragma unroll
        for (int reg = 0; reg < 4; ++reg) {
            int gr = rowBase + wr * 64 + i * 16 + quad * 4 + reg;
            if (gr < n) {
                float sc = (EPI == 0 && rowScale) ? rowScale[gr] : 1.f;
#pragma unroll
                for (int j = 0; j < 4; ++j) {
                    int gc = colBase + wc * 64 + j * 16 + ml;
                    float v = acc[i][j][reg];
                    if (EPI == 1) v += bias[gc];
                    C[(size_t)gr * strideC + gc] = convert_out(v * sc, (OutT*)nullptr);
                }
            }
        }
    }
}

// ---------------- conv1+conv2 fused GEMM ----------------
// Phase 1: h1 = ax @ Wt1 + b1 (K=64)  -> hcat[:,0:128] (bf16 global) AND a
//          32KB LDS tile H1 stored in the As-swizzled MFMA fragment layout.
// Phase 2: xw8 = fp8(dinv[row] * (h1 @ Wt2)) (K=128), A read from H1 (LDS).
// LDS map: [0,8K) Bs (both phases) | [8K,16K) As (phase 1) aliased by
//          [8K,40K) H1 (phase 2). 40KB -> 4 blocks/CU.
__launch_bounds__(256, 4)
__global__ void conv12_gemm(const bf16* __restrict__ A,
                            const bf16* __restrict__ Wt1, const float* __restrict__ b1,
                            const bf16* __restrict__ Wt2, const float* __restrict__ dinv,
                            bf16* __restrict__ hcat, fp8s* __restrict__ xw8, int n) {
    __shared__ char smem[40960];
    bf16* Bs = (bf16*)smem;
    bf16* As = (bf16*)(smem + 8192);
    bf16* H1 = (bf16*)(smem + 8192);   // 4 k-tiles x 8KB, overwrites As

    int t = threadIdx.x;
    int rowBase = blockIdx.x * 128;
    int lane = t & 63;
    int wv   = t >> 6;
    int wr   = wv >> 1, wc = wv & 1;
    int ml   = lane & 15, quad = lane >> 4;
    int srow0 = wv * 32 + (lane >> 2);
    int cchunk = lane & 3;

    f32x4 acc[4][4];
#pragma unroll
    for (int i = 0; i < 4; ++i)
#pragma unroll
        for (int j = 0; j < 4; ++j) acc[i][j] = (f32x4){0.f, 0.f, 0.f, 0.f};

    // ---- phase 1: K=64, A = ax, B = Wt1 ----
    for (int kt = 0; kt < 64; kt += 32) {
        __syncthreads();
#pragma unroll
        for (int inst = 0; inst < 2; ++inst) {
            int r  = srow0 + inst * 16;
            int gc = (cchunk ^ (r & 3)) * 8;
            int gr = rowBase + r; if (gr >= n) gr = n - 1;
            load_lds16(A + (size_t)gr * 64 + kt + gc,
                       &As[(wv * 128 + inst * 64) * 8]);
            load_lds16(Wt1 + (size_t)r * 64 + kt + gc,
                       &Bs[(wv * 128 + inst * 64) * 8]);
        }
        __syncthreads();
        bf16x8 af[4], bfv[4];
#pragma unroll
        for (int i = 0; i < 4; ++i) {
            int ra = wr * 64 + i * 16 + ml;
            int rb = wc * 64 + i * 16 + ml;
            af[i]  = *(const bf16x8*)&As[(ra * 4 + (quad ^ (ra & 3))) * 8];
            bfv[i] = *(const bf16x8*)&Bs[(rb * 4 + (quad ^ (rb & 3))) * 8];
        }
#pragma unroll
        for (int i = 0; i < 4; ++i)
#pragma unroll
            for (int j = 0; j < 4; ++j)
                acc[i][j] = __builtin_amdgcn_mfma_f32_16x16x32_bf16(
                    af[i], bfv[j], acc[i][j], 0, 0, 0);
    }
    __syncthreads();   // As/Bs reads done in ALL threads before H1 overwrites As

    // ---- epilogue 1: +b1, write hcat[:,0:128] and H1 (swizzled bf16) ----
    {
        float b4[4];
#pragma unroll
        for (int j = 0; j < 4; ++j) b4[j] = b1[wc * 64 + j * 16 + ml];
#pragma unroll
        for (int i = 0; i < 4; ++i) {
#pragma unroll
            for (int reg = 0; reg < 4; ++reg) {
                int r  = wr * 64 + i * 16 + quad * 4 + reg;
                int gr = rowBase + r;
#pragma unroll
                for (int j = 0; j < 4; ++j) {
                    int c  = wc * 64 + j * 16 + ml;
                    bf16 bv = (bf16)(acc[i][j][reg] + b4[j]);
                    int kt2 = c >> 5, cc = c & 31;
                    H1[kt2 * 4096 + (r * 4 + ((cc >> 3) ^ (r & 3))) * 8 + (cc & 7)] = bv;
                    if (gr < n) hcat[(size_t)gr * 384 + c] = bv;
                }
            }
        }
    }

#pragma unroll
    for (int i = 0; i < 4; ++i)
#pragma unroll
        for (int j = 0; j < 4; ++j) acc[i][j] = (f32x4){0.f, 0.f, 0.f, 0.f};

    // ---- phase 2: K=128, A = H1 (LDS-resident), B = Wt2 ----
    for (int kt = 0; kt < 4; ++kt) {
        __syncthreads();
#pragma unroll
        for (int inst = 0; inst < 2; ++inst) {
            int r  = srow0 + inst * 16;
            int gc = (cchunk ^ (r & 3)) * 8;
            load_lds16(Wt2 + (size_t)r * 128 + kt * 32 + gc,
                       &Bs[(wv * 128 + inst * 64) * 8]);
        }
        __syncthreads();
        bf16x8 af[4], bfv[4];
#pragma unroll
        for (int i = 0; i < 4; ++i) {
            int ra = wr * 64 + i * 16 + ml;
            int rb = wc * 64 + i * 16 + ml;
            af[i]  = *(const bf16x8*)&H1[kt * 4096 + (ra * 4 + (quad ^ (ra & 3))) * 8];
            bfv[i] = *(const bf16x8*)&Bs[(rb * 4 + (quad ^ (rb & 3))) * 8];
        }
#pragma unroll
        for (int i = 0; i < 4; ++i)
#pragma unroll
            for (int j = 0; j < 4; ++j)
                acc[i][j] = __builtin_amdgcn_mfma_f32_16x16x32_bf16(
                    af[i], bfv[j], acc[i][j], 0, 0, 0);
    }

    // ---- epilogue 2: xw8 = fp8(dinv[row] * acc) ----
#pragma unroll
    for (int i = 0; i < 4; ++i) {
#pragma unroll
        for (int reg = 0; reg < 4; ++reg) {
            int gr = rowBase + wr * 64 + i * 16 + quad * 4 + reg;
            if (gr < n) {
                float sc = dinv[gr];
#pragma unroll
                for (int j = 0; j < 4; ++j) {
                    int c = wc * 64 + j * 16 + ml;
                    xw8[(size_t)gr * 128 + c] =
                        convert_out(acc[i][j][reg] * sc, (fp8s*)nullptr);
                }
            }
        }
    }
}

// ---------------- fused MLP head (k-tile-stationary, BM=128, all 3 slabs) --------
// 128 rows/block, grid (N+127)/128. Per 32-K step: stage one A tile (8KB) +
// all three lW1 slab tiles (3x8KB); accumulate acc[3][4][4] (~224 VGPR,
// launch_bounds(256,2)). hcat read ONCE; 48 MFMA per barrier.
__launch_bounds__(256, 2)
__global__ void head_gemm(const bf16* __restrict__ A, const bf16* __restrict__ Bt,
                          const float* __restrict__ lb1, const float* __restrict__ lW2,
                          const float* __restrict__ lb2,
                          float* __restrict__ out, int n) {
    __shared__ bf16 As[128 * 32];
    __shared__ bf16 Bs[3][128 * 32];
    __shared__ float plds[2][128][2];
    int t = threadIdx.x;
    int rowBase = blockIdx.x * 128;
    int lane = t & 63;
    int wv   = t >> 6;
    int wr   = wv >> 1, wc = wv & 1;
    int ml   = lane & 15, quad = lane >> 4;
    int srow0 = wv * 32 + (lane >> 2);          // 128 rows over 4 waves x 2 insts
    int cchunk = lane & 3;

    f32x4 acc[3][4][4];
#pragma unroll
    for (int s = 0; s < 3; ++s)
#pragma unroll
        for (int i = 0; i < 4; ++i)
#pragma unroll
            for (int j = 0; j < 4; ++j) acc[s][i][j] = (f32x4){0.f, 0.f, 0.f, 0.f};

    for (int kt = 0; kt < 384; kt += 32) {
        __syncthreads();
#pragma unroll
        for (int inst = 0; inst < 2; ++inst) {
            int r  = srow0 + inst * 16;
            int gc = (cchunk ^ (r & 3)) * 8;
            int gr = rowBase + r; if (gr >= n) gr = n - 1;
            load_lds16(A + (size_t)gr * 384 + kt + gc,
                       &As[(wv * 128 + inst * 64) * 8]);
#pragma unroll
            for (int s = 0; s < 3; ++s)
                load_lds16(Bt + (size_t)(s * 128 + r) * 384 + kt + gc,
                           &Bs[s][(wv * 128 + inst * 64) * 8]);
        }
        __syncthreads();
        bf16x8 af[4];
#pragma unroll
        for (int i = 0; i < 4; ++i) {
            int ra = wr * 64 + i * 16 + ml;
            af[i] = *(const bf16x8*)&As[(ra * 4 + (quad ^ (ra & 3))) * 8];
        }
#pragma unroll
        for (int s = 0; s < 3; ++s)
#pragma unroll
            for (int j = 0; j < 4; ++j) {
                int rb = wc * 64 + j * 16 + ml;
                bf16x8 bv = *(const bf16x8*)&Bs[s][(rb * 4 + (quad ^ (rb & 3))) * 8];
#pragma unroll
                for (int i = 0; i < 4; ++i)
                    acc[s][i][j] = __builtin_amdgcn_mfma_f32_16x16x32_bf16(
                        af[i], bv, acc[s][i][j], 0, 0, 0);
            }
    }

    // epilogue: relu(+lb1) @ lW2^T, summed over slabs+cols in-register
    float b4[3][4], w0[3][4], w1[3][4];
#pragma unroll
    for (int s = 0; s < 3; ++s)
#pragma unroll
        for (int j = 0; j < 4; ++j) {
            int gc = s * 128 + wc * 64 + j * 16 + ml;
            b4[s][j] = lb1[gc];
            w0[s][j] = lW2[gc];
            w1[s][j] = lW2[384 + gc];
        }
#pragma unroll
    for (int i = 0; i < 4; ++i) {
#pragma unroll
        for (int reg = 0; reg < 4; ++reg) {
            float p0 = 0.f, p1 = 0.f;
#pragma unroll
            for (int s = 0; s < 3; ++s)
#pragma unroll
                for (int j = 0; j < 4; ++j) {
                    float v = fmaxf(acc[s][i][j][reg] + b4[s][j], 0.f);
                    p0 += v * w0[s][j];
                    p1 += v * w1[s][j];
                }
#pragma unroll
            for (int m = 1; m < 16; m <<= 1) {
                p0 += __shfl_xor(p0, m, 64);
                p1 += __shfl_xor(p1, m, 64);
            }
            if (ml == 0) {
                int rl = wr * 64 + i * 16 + quad * 4 + reg;
                plds[wc][rl][0] = p0;           // unique writer per (wc,rl)
                plds[wc][rl][1] = p1;
            }
        }
    }

    __syncthreads();
    if (t < 128) {
        int gr = rowBase + t;
        if (gr < n) {
            float l0 = plds[0][t][0] + plds[1][t][0] + lb2[0];
            float l1 = plds[0][t][1] + plds[1][t][1] + lb2[1];
            size_t seg = (size_t)n * 2;
            *(float2*)(out + (size_t)gr * 2) = make_float2(l0, l1);
            float m  = fmaxf(l0, l1);
            float e0 = expf(l0 - m), e1 = expf(l1 - m);
            float inv = 1.f / (e0 + e1);
            *(float2*)(out + seg + (size_t)gr * 2) = make_float2(e0 * inv, e1 * inv);
        }
    }
}

// ---------------- aggregation (slice-owned, 8 lanes/node) ----------------
// 8 lanes per node; lane owns a 16B slice of the row and accumulates it
// over all edges serially. col[j] broadcast within the group. No shuffles.

// 64-dim bf16 rows (128B): lane covers cols [sub*8, +8).
__launch_bounds__(256)
__global__ void aggregate64(const bf16* __restrict__ xs, const int* __restrict__ rpS,
                            const int* __restrict__ rpE,
                            const int* __restrict__ col, const float* __restrict__ dinv,
                            bf16* __restrict__ out, int n) {
    int gid = blockIdx.x * 256 + threadIdx.x;
    int v   = gid >> 3;
    int sub = gid & 7;
    if (v >= n) return;
    float di = dinv[v];
    int b = rpS[v], e = rpE[v];
    const bf16* base = xs + sub * 8;
    float acc[8] = {0.f, 0.f, 0.f, 0.f, 0.f, 0.f, 0.f, 0.f};
    int j = b;
    for (; j + 2 <= e; j += 2) {
        int s0 = col[j], s1 = col[j + 1];
        bf16x8 m0 = *(const bf16x8*)(base + (size_t)s0 * 64);
        bf16x8 m1 = *(const bf16x8*)(base + (size_t)s1 * 64);
#pragma unroll
        for (int k = 0; k < 8; ++k) acc[k] += (float)m0[k] + (float)m1[k];
    }
    if (j < e) {
        int s = col[j];
        bf16x8 m = *(const bf16x8*)(base + (size_t)s * 64);
#pragma unroll
        for (int k = 0; k < 8; ++k) acc[k] += (float)m[k];
    }
    bf16x8 mv = *(const bf16x8*)(base + (size_t)v * 64);
    bf16x8 o;
#pragma unroll
    for (int k = 0; k < 8; ++k) o[k] = (bf16)(di * (acc[k] + (float)mv[k]));
    *(bf16x8*)(out + (size_t)v * 64 + sub * 8) = o;
}

// 128-dim fp8 rows (128B): lane covers cols [sub*16, +16).
__launch_bounds__(256)
__global__ void aggregate_fp8(const fp8s* __restrict__ xs, const int* __restrict__ rpS,
                              const int* __restrict__ rpE,
                              const int* __restrict__ col, const float* __restrict__ dinv,
                              const float* __restrict__ bias, bf16* __restrict__ out,
                              int outStride, int n) {
    int gid = blockIdx.x * 256 + threadIdx.x;
    int v   = gid >> 3;
    int sub = gid & 7;
    if (v >= n) return;
    float di = dinv[v];
    int b = rpS[v], e = rpE[v];
    const fp8s* base = xs + sub * 16;
    float acc[16];
#pragma unroll
    for (int k = 0; k < 16; ++k) acc[k] = 0.f;
    int j = b;
    for (; j + 2 <= e; j += 2) {
        int s0 = col[j], s1 = col[j + 1];
        uint4 p0 = *(const uint4*)(base + (size_t)s0 * 128);
        uint4 p1 = *(const uint4*)(base + (size_t)s1 * 128);
        float4 a0 = fp8x4_to_f4(p0.x), b0 = fp8x4_to_f4(p0.y),
               c0 = fp8x4_to_f4(p0.z), d0 = fp8x4_to_f4(p0.w);
        float4 a1 = fp8x4_to_f4(p1.x), b1v = fp8x4_to_f4(p1.y),
               c1 = fp8x4_to_f4(p1.z), d1 = fp8x4_to_f4(p1.w);
        acc[0]  += a0.x + a1.x;  acc[1]  += a0.y + a1.y;
        acc[2]  += a0.z + a1.z;  acc[3]  += a0.w + a1.w;
        acc[4]  += b0.x + b1v.x; acc[5]  += b0.y + b1v.y;
        acc[6]  += b0.z + b1v.z; acc[7]  += b0.w + b1v.w;
        acc[8]  += c0.x + c1.x;  acc[9]  += c0.y + c1.y;
        acc[10] += c0.z + c1.z;  acc[11] += c0.w + c1.w;
        acc[12] += d0.x + d1.x;  acc[13] += d0.y + d1.y;
        acc[14] += d0.z + d1.z;  acc[15] += d0.w + d1.w;
    }
    if (j < e) {
        int s = col[j];
        uint4 p = *(const uint4*)(base + (size_t)s * 128);
        float4 f0 = fp8x4_to_f4(p.x), f1 = fp8x4_to_f4(p.y),
               f2 = fp8x4_to_f4(p.z), f3 = fp8x4_to_f4(p.w);
        acc[0]  += f0.x; acc[1]  += f0.y; acc[2]  += f0.z; acc[3]  += f0.w;
        acc[4]  += f1.x; acc[5]  += f1.y; acc[6]  += f1.z; acc[7]  += f1.w;
        acc[8]  += f2.x; acc[9]  += f2.y; acc[10] += f2.z; acc[11] += f2.w;
        acc[12] += f3.x; acc[13] += f3.y; acc[14] += f3.z; acc[15] += f3.w;
    }
    uint4 pv = *(const uint4*)(base + (size_t)v * 128);
    float4 f0 = fp8x4_to_f4(pv.x), f1 = fp8x4_to_f4(pv.y),
           f2 = fp8x4_to_f4(pv.z), f3 = fp8x4_to_f4(pv.w);
    float fv[16] = {f0.x, f0.y, f0.z, f0.w, f1.x, f1.y, f1.z, f1.w,
                    f2.x, f2.y, f2.z, f2.w, f3.x, f3.y, f3.z, f3.w};
    const float* bb = bias + sub * 16;
    bf16x8 o0, o1;
#pragma unroll
    for (int k = 0; k < 8; ++k)
        o0[k] = (bf16)(di * (acc[k] + fv[k]) + bb[k]);
#pragma unroll
    for (int k = 0; k < 8; ++k)
        o1[k] = (bf16)(di * (acc[8 + k] + fv[8 + k]) + bb[8 + k]);
    bf16* op = out + (size_t)v * outStride + sub * 16;
    *(bf16x8*)op = o0;
    *(bf16x8*)(op + 8) = o1;
}

extern "C" void kernel_launch(void* const* d_in, const int* in_sizes, int n_in,
                              void* d_out, int out_size, void* d_ws, size_t ws_size,
                              hipStream_t stream) {
    const float* x   = (const float*)d_in[0];
    const int*   ei  = (const int*)d_in[1];
    const float* W1  = (const float*)d_in[2];
    const float* b1  = (const float*)d_in[3];
    const float* W2  = (const float*)d_in[4];
    const float* b2  = (const float*)d_in[5];
    const float* W3  = (const float*)d_in[6];
    const float* b3  = (const float*)d_in[7];
    const float* lW1 = (const float*)d_in[8];
    const float* lb1 = (const float*)d_in[9];
    const float* lW2 = (const float*)d_in[10];
    const float* lb2 = (const float*)d_in[11];
    float* out = (float*)d_out;

    int N = in_sizes[0] / 64;
    int E = in_sizes[1] / 2;
    const int* src = ei;
    const int* dst = ei + E;

    char* ws = (char*)d_ws;
    size_t off = 0;
    auto take = [&](size_t bytes) -> char* {
        char* p = ws + off;
        off += (bytes + 255) & ~(size_t)255;
        return p;
    };
    int nBlk  = (N + 255) / 256;
    int nbuck = nBlk;
    int*   cnt    = (int*)take((size_t)N * 4);         // fallback only
    int*   fill   = (int*)take((size_t)N * 4);         // fallback only
    int*   rpS    = (int*)take((size_t)N * 4);
    int*   rpE    = (int*)take((size_t)N * 4);
    float* dinv   = (float*)take((size_t)N * 4);
    int*   bsum   = (int*)take((size_t)nBlk * 4);      // fallback only
    int*   gcount = (int*)take((size_t)nbuck * 4);
    size_t regionE = (nbuck <= 256 && N <= 65536)
                   ? (size_t)nbuck * BUCKET_CAP : (size_t)E;
    int*   col    = (int*)take(regionE * 4);
    unsigned int* pairs = (unsigned int*)take(regionE * 4);
    bf16*  xs0    = (bf16*)take((size_t)N * 64 * 2);
    bf16*  ax     = (bf16*)take((size_t)N * 64 * 2);
    bf16*  Wt1    = (bf16*)take((size_t)64 * 128 * 2);
    bf16*  Wt2    = (bf16*)take((size_t)128 * 128 * 2);
    bf16*  Wt3    = (bf16*)take((size_t)128 * 128 * 2);
    bf16*  lW1_bf = (bf16*)take((size_t)384 * 384 * 2);
    fp8s*  xw8    = (fp8s*)take((size_t)N * 128);
    bf16*  hcat   = (bf16*)take((size_t)N * 384 * 2);

    // CSR build + prep: memset + bin_prep(4x blocks, +weights) + fill + xs0
    if (nbuck <= 256 && N <= 65536) {
        int nbin = nbuck * 4;
        hipMemsetAsync(gcount, 0, (size_t)nbuck * 4, stream);
        bin_prep<<<nbin + 736, 256, 0, stream>>>(
            src, dst, gcount, pairs, E, nbin,
            W1, W2, W3, lW1, Wt1, Wt2, Wt3, lW1_bf);
        csr_fill_full<<<nbuck, 256, 0, stream>>>(
            pairs, gcount, rpS, rpE, dinv, col, N);
        xs0_prep<<<(N * 8 + 255) / 256, 256, 0, stream>>>(x, dinv, xs0, N);
    } else {
        bin_prep<<<736, 256, 0, stream>>>(                 // weights only
            src, dst, gcount, pairs, 0, 0,
            W1, W2, W3, lW1, Wt1, Wt2, Wt3, lW1_bf);
        init_kernel<<<nBlk, 256, 0, stream>>>(cnt, fill, N);
        hist_kernel<<<(E + 255) / 256, 256, 0, stream>>>(dst, cnt, E);
        block_reduce<<<nBlk, 256, 0, stream>>>(cnt, bsum, N);
        scan_bsums<<<1, 256, 0, stream>>>(bsum, nBlk);
        write_rp_fb<<<nBlk, 256, 0, stream>>>(cnt, bsum, x, rpS, rpE, dinv, xs0, N);
        fill_kernel<<<(E + 255) / 256, 256, 0, stream>>>(src, dst, rpS, fill, col, E);
    }

    int gemmBlocks = (N + 127) / 128;
    int aggBlocks  = (N + 31) / 32;

    // conv1+conv2: aggregate (64-dim bf16), then fused GEMM pair
    //   h1 = ax@Wt1+b1 -> hcat[:,0:128];  xw8 = fp8(dinv * h1@Wt2)
    aggregate64<<<aggBlocks, 256, 0, stream>>>(xs0, rpS, rpE, col, dinv, ax, N);
    conv12_gemm<<<gemmBlocks, 256, 0, stream>>>(
        ax, Wt1, b1, Wt2, dinv, hcat, xw8, N);
    // conv2 aggregate (+b2), conv3 GEMM, conv3 aggregate (+b3)
    aggregate_fp8<<<aggBlocks, 256, 0, stream>>>(xw8, rpS, rpE, col, dinv, b2, hcat + 128, 384, N);
    mfma_gemm<0, fp8s><<<dim3(gemmBlocks, 1), 256, 0, stream>>>(
        hcat + 128, 384, 128, Wt3, nullptr, dinv, xw8, 128, N);
    aggregate_fp8<<<aggBlocks, 256, 0, stream>>>(xw8, rpS, rpE, col, dinv, b3, hcat + 256, 384, N);

    // fused MLP head: BM=128 k-tile-stationary, hcat read once, softmax in-block
    head_gemm<<<gemmBlocks, 256, 0, stream>>>(hcat, lW1_bf, lb1, lW2, lb2, out, N);
}

// Round 10
// 220.763 us; speedup vs baseline: 1.0326x; 1.0326x over previous
//
#include <hip/hip_runtime.h>
#include <hip/hip_bf16.h>
#include <hip/hip_fp8.h>
#include <cmath>

// ---------------------------------------------------------------------------
// Round 25. Base: R23 @ 223.4us (best). R24 (build-TLP split) was flat/+4.6
//   -> build was never the residual (R22->R23 delta implies bucket build
//   ~12-15us total). REVERTED to R23 build (xs0 inside csr_fill, nbuck-block
//   binning).
//   - ONE lever: aggregate inner loops unrolled x2 -> x4 (4 independent
//     128B row-gathers in flight per lane). If aggregates are latency-bound
//     this is -20-30% each; if L3-BW-floored it is flat and the pipeline is
//     near its structural floor.
//   - (R23) BM=128 head; (R20) slice-owned aggregates; (R17) k-tile-
//     stationary head; (R16) conv12 H1-LDS fusion; (R14) bucket CSR build;
//     (R11) fp8 xw; bf16 MFMA 128x128/BK32 + XOR-swizzled LDS +
//     global_load_lds w16.
// ---------------------------------------------------------------------------

typedef __bf16 bf16;
typedef __bf16 bf16x2 __attribute__((ext_vector_type(2)));
typedef __bf16 bf16x4 __attribute__((ext_vector_type(4)));
typedef __bf16 bf16x8 __attribute__((ext_vector_type(8)));
typedef float  f32x4  __attribute__((ext_vector_type(4)));
typedef unsigned char fp8s;   // e4m3 storage byte

#define BUCKET_CAP 8192       // expected load 4096 (Poisson), overflow ~impossible

__device__ __forceinline__ void load_lds16(const bf16* g, bf16* l) {
    __builtin_amdgcn_global_load_lds(
        (const __attribute__((address_space(1))) void*)g,
        (__attribute__((address_space(3))) void*)l, 16, 0, 0);
}

__device__ __forceinline__ bf16 convert_out(float v, bf16*) { return (bf16)v; }
__device__ __forceinline__ fp8s convert_out(float v, fp8s*) {
    __hip_fp8_e4m3 q(v); return (fp8s)q.__x;
}

__device__ __forceinline__ float4 fp8x4_to_f4(unsigned int p) {
    __hip_fp8x2_e4m3 lo, hi;
    lo.__x = (__hip_fp8x2_storage_t)(p & 0xffffu);
    hi.__x = (__hip_fp8x2_storage_t)(p >> 16);
    float2 a = (float2)lo, c = (float2)hi;
    return make_float4(a.x, a.y, c.x, c.y);
}

// ---------------- CSR build (fixed-capacity buckets, N <= 65536) ----------------

// blocks [0,nbuck): bin edges by dst>>8 into pairs[b*CAP ..] — per-block LDS
// hist, one global atomicAdd per touched bucket for the run base.
// blocks [nbuck, nbuck+736): weight transpose/cast (independent work).
__launch_bounds__(256)
__global__ void bin_prep(const int* __restrict__ src, const int* __restrict__ dst,
                         int* __restrict__ gcount, unsigned int* __restrict__ pairs,
                         int e, int nbuck,
                         const float* __restrict__ W1, const float* __restrict__ W2,
                         const float* __restrict__ W3, const float* __restrict__ lW1,
                         bf16* __restrict__ Wt1, bf16* __restrict__ Wt2,
                         bf16* __restrict__ Wt3, bf16* __restrict__ lW1_bf) {
    int t = threadIdx.x;
    if ((int)blockIdx.x >= nbuck) {
        int i = (blockIdx.x - nbuck) * 256 + t;
        if (i < 8192) {
            int k = i >> 7, c = i & 127; Wt1[c * 64 + k] = (bf16)W1[i];
        } else if (i < 24576) {
            int j = i - 8192; int k = j >> 7, c = j & 127; Wt2[c * 128 + k] = (bf16)W2[j];
        } else if (i < 40960) {
            int j = i - 24576; int k = j >> 7, c = j & 127; Wt3[c * 128 + k] = (bf16)W3[j];
        } else if (i < 188416) {
            int j = i - 40960; lW1_bf[j] = (bf16)lW1[j];
        }
        return;
    }
    __shared__ int hist[256], base[256], cur[256];
    hist[t] = 0; cur[t] = 0;
    __syncthreads();
    int perBlock = (e + nbuck - 1) / nbuck;
    int lo = blockIdx.x * perBlock;
    int hi = lo + perBlock; if (hi > e) hi = e;
    for (int i = lo + t; i < hi; i += 256)
        atomicAdd(&hist[dst[i] >> 8], 1);
    __syncthreads();
    if (hist[t] > 0) base[t] = atomicAdd(&gcount[t], hist[t]);
    __syncthreads();
    for (int i = lo + t; i < hi; i += 256) {
        int d = dst[i];
        int b = d >> 8;
        int r = base[b] + atomicAdd(&cur[b], 1);
        if (r < BUCKET_CAP)   // overflow guard (statistically impossible)
            pairs[(size_t)b * BUCKET_CAP + r] = (unsigned)src[i] | ((unsigned)(d & 255) << 16);
    }
}

// one block per bucket (region [b*CAP, b*CAP+gcount[b])): per-node counts ->
// rpS/rpE + dinv; LDS-window scatter -> coalesced col; xs0 = bf16(dinv * x).
#define FILL_CAP 6144
__launch_bounds__(256)
__global__ void csr_fill_full(const unsigned int* __restrict__ pairs,
                              const int* __restrict__ gcount,
                              const float* __restrict__ x,
                              int* __restrict__ rpS, int* __restrict__ rpE,
                              float* __restrict__ dinv,
                              int* __restrict__ col, bf16* __restrict__ xs0, int n) {
    __shared__ int cnt[256];
    __shared__ int ofs[256];
    __shared__ int ss[256];
    __shared__ float dinv_l[256];
    __shared__ int win[FILL_CAP];
    int b = blockIdx.x, t = threadIdx.x;
    int nodeBase = b << 8;
    int nhi = n - nodeBase; if (nhi > 256) nhi = 256;
    int lo = b * BUCKET_CAP;
    int bcountE = gcount[b]; if (bcountE > BUCKET_CAP) bcountE = BUCKET_CAP;
    cnt[t] = 0;
    __syncthreads();
    for (int i = t; i < bcountE; i += 256)
        atomicAdd(&cnt[pairs[lo + i] >> 16], 1);
    __syncthreads();
    int myc = cnt[t];
    ss[t] = myc;
    __syncthreads();
#pragma unroll
    for (int off = 1; off < 256; off <<= 1) {
        int tmp = (t >= off) ? ss[t - off] : 0;
        __syncthreads();
        ss[t] += tmp;
        __syncthreads();
    }
    int excl = ss[t] - myc;
    ofs[t] = excl;
    int node = nodeBase + t;
    float d = rsqrtf((float)(myc + 1));
    dinv_l[t] = d;
    if (node < n) {
        rpS[node] = lo + excl;
        rpE[node] = lo + excl + myc;
        dinv[node] = d;                          // +1 self-loop
    }
    cnt[t] = 0;
    __syncthreads();
    if (bcountE <= FILL_CAP) {
        for (int i = t; i < bcountE; i += 256) {
            unsigned p = pairs[lo + i];
            int dl = (int)(p >> 16);
            int r = atomicAdd(&cnt[dl], 1);
            win[ofs[dl] + r] = (int)(p & 0xffffu);
        }
        __syncthreads();
        for (int i = t; i < bcountE; i += 256) col[lo + i] = win[i];
    } else {
        for (int i = t; i < bcountE; i += 256) {
            unsigned p = pairs[lo + i];
            int dl = (int)(p >> 16);
            int r = atomicAdd(&cnt[dl], 1);
            col[lo + ofs[dl] + r] = (int)(p & 0xffffu);
        }
    }
    // xs0 = bf16(dinv[row] * x[row]) for this block's nodes (coalesced)
    int tot = nhi * 64;
    const float* xb = x + (size_t)nodeBase * 64;
    bf16* ob = xs0 + (size_t)nodeBase * 64;
    for (int idx = t; idx < tot; idx += 256)
        ob[idx] = (bf16)(xb[idx] * dinv_l[idx >> 6]);
}

// -------- fallback CSR build for N > 65536 (not used at this size) --------

__launch_bounds__(256)
__global__ void init_kernel(int* __restrict__ cnt, int* __restrict__ fill, int n) {
    int i = blockIdx.x * 256 + threadIdx.x;
    if (i < n) { cnt[i] = 1; fill[i] = 0; }
}

__launch_bounds__(256)
__global__ void hist_kernel(const int* __restrict__ dst, int* __restrict__ cnt, int e) {
    int i = blockIdx.x * 256 + threadIdx.x;
    if (i < e) atomicAdd(&cnt[dst[i]], 1);
}

__launch_bounds__(256)
__global__ void block_reduce(const int* __restrict__ cnt, int* __restrict__ bsum, int n) {
    __shared__ int s[256];
    int t = threadIdx.x;
    int i = blockIdx.x * 256 + t;
    int v = (i < n) ? cnt[i] - 1 : 0;
    s[t] = v;
    __syncthreads();
#pragma unroll
    for (int off = 128; off > 0; off >>= 1) {
        if (t < off) s[t] += s[t + off];
        __syncthreads();
    }
    if (t == 0) bsum[blockIdx.x] = s[0];
}

__launch_bounds__(256)
__global__ void scan_bsums(int* __restrict__ bsum, int nb) {
    __shared__ int s[256];
    int t = threadIdx.x;
    int v = (t < nb) ? bsum[t] : 0;
    s[t] = v;
    __syncthreads();
#pragma unroll
    for (int off = 1; off < 256; off <<= 1) {
        int tmp = (t >= off) ? s[t - off] : 0;
        __syncthreads();
        s[t] += tmp;
        __syncthreads();
    }
    if (t < nb) bsum[t] = s[t] - v;
}

__launch_bounds__(256)
__global__ void write_rp_fb(const int* __restrict__ cnt, const int* __restrict__ bsum,
                            const float* __restrict__ x,
                            int* __restrict__ rpS, int* __restrict__ rpE,
                            float* __restrict__ dinv,
                            bf16* __restrict__ xs0, int n) {
    __shared__ int s[256];
    int t = threadIdx.x;
    int i = blockIdx.x * 256 + t;
    int c = (i < n) ? cnt[i] : 1;
    int v = c - 1;
    s[t] = v;
    __syncthreads();
#pragma unroll
    for (int off = 1; off < 256; off <<= 1) {
        int tmp = (t >= off) ? s[t - off] : 0;
        __syncthreads();
        s[t] += tmp;
        __syncthreads();
    }
    if (i < n) {
        int start = bsum[blockIdx.x] + s[t] - v;
        rpS[i] = start;
        rpE[i] = start + v;
        float d = rsqrtf((float)c);
        dinv[i] = d;
        for (int k = 0; k < 64; ++k)
            xs0[(size_t)i * 64 + k] = (bf16)(x[(size_t)i * 64 + k] * d);
    }
}

__launch_bounds__(256)
__global__ void fill_kernel(const int* __restrict__ src, const int* __restrict__ dst,
                            const int* __restrict__ rpS, int* __restrict__ fill,
                            int* __restrict__ col, int e) {
    int i = blockIdx.x * 256 + threadIdx.x;
    if (i < e) {
        int d = dst[i];
        int pos = rpS[d] + atomicAdd(&fill[d], 1);
        col[pos] = src[i];
    }
}

// ---------------- MFMA GEMM (generic, EPI: 0 = rowScale, 1 = +bias) ----------------
template<int EPI, typename OutT>
__launch_bounds__(256, 4)
__global__ void mfma_gemm(const bf16* __restrict__ A, int strideA, int K,
                          const bf16* __restrict__ Bt,
                          const float* __restrict__ bias,
                          const float* __restrict__ rowScale,
                          OutT* __restrict__ C, int strideC, int n) {
    __shared__ bf16 As[128 * 32];
    __shared__ bf16 Bs[128 * 32];
    int t = threadIdx.x;
    int rowBase = blockIdx.x * 128;
    int colBase = blockIdx.y * 128;

    int lane = t & 63;
    int wv   = t >> 6;
    int wr   = wv >> 1, wc = wv & 1;
    int ml   = lane & 15, quad = lane >> 4;

    f32x4 acc[4][4];
#pragma unroll
    for (int i = 0; i < 4; ++i)
#pragma unroll
        for (int j = 0; j < 4; ++j) acc[i][j] = (f32x4){0.f, 0.f, 0.f, 0.f};

    int srow0 = wv * 32 + (lane >> 2);
    int cchunk = lane & 3;

    for (int kt = 0; kt < K; kt += 32) {
        __syncthreads();
#pragma unroll
        for (int inst = 0; inst < 2; ++inst) {
            int r  = srow0 + inst * 16;
            int gc = (cchunk ^ (r & 3)) * 8;
            int gr = rowBase + r; if (gr >= n) gr = n - 1;
            load_lds16(A + (size_t)gr * strideA + kt + gc,
                       &As[(wv * 128 + inst * 64) * 8]);
            int br = colBase + r;
            load_lds16(Bt + (size_t)br * K + kt + gc,
                       &Bs[(wv * 128 + inst * 64) * 8]);
        }
        __syncthreads();
        bf16x8 af[4], bfv[4];
#pragma unroll
        for (int i = 0; i < 4; ++i) {
            int ra = wr * 64 + i * 16 + ml;
            int rb = wc * 64 + i * 16 + ml;
            af[i]  = *(const bf16x8*)&As[(ra * 4 + (quad ^ (ra & 3))) * 8];
            bfv[i] = *(const bf16x8*)&Bs[(rb * 4 + (quad ^ (rb & 3))) * 8];
        }
#pragma unroll
        for (int i = 0; i < 4; ++i)
#pragma unroll
            for (int j = 0; j < 4; ++j)
                acc[i][j] = __builtin_amdgcn_mfma_f32_16x16x32_bf16(
                    af[i], bfv[j], acc[i][j], 0, 0, 0);
    }

#pragma unroll
    for (int i = 0; i < 4; ++i) {
#pragma unroll
        for (int reg = 0; reg < 4; ++reg) {
            int gr = rowBase + wr * 64 + i * 16 + quad * 4 + reg;
            if (gr < n) {
                float sc = (EPI == 0 && rowScale) ? rowScale[gr] : 1.f;
#pragma unroll
                for (int j = 0; j < 4; ++j) {
                    int gc = colBase + wc * 64 + j * 16 + ml;
                    float v = acc[i][j][reg];
                    if (EPI == 1) v += bias[gc];
                    C[(size_t)gr * strideC + gc] = convert_out(v * sc, (OutT*)nullptr);
                }
            }
        }
    }
}

// ---------------- conv1+conv2 fused GEMM ----------------
// Phase 1: h1 = ax @ Wt1 + b1 (K=64)  -> hcat[:,0:128] (bf16 global) AND a
//          32KB LDS tile H1 stored in the As-swizzled MFMA fragment layout.
// Phase 2: xw8 = fp8(dinv[row] * (h1 @ Wt2)) (K=128), A read from H1 (LDS).
// LDS map: [0,8K) Bs (both phases) | [8K,16K) As (phase 1) aliased by
//          [8K,40K) H1 (phase 2). 40KB -> 4 blocks/CU.
__launch_bounds__(256, 4)
__global__ void conv12_gemm(const bf16* __restrict__ A,
                            const bf16* __restrict__ Wt1, const float* __restrict__ b1,
                            const bf16* __restrict__ Wt2, const float* __restrict__ dinv,
                            bf16* __restrict__ hcat, fp8s* __restrict__ xw8, int n) {
    __shared__ char smem[40960];
    bf16* Bs = (bf16*)smem;
    bf16* As = (bf16*)(smem + 8192);
    bf16* H1 = (bf16*)(smem + 8192);   // 4 k-tiles x 8KB, overwrites As

    int t = threadIdx.x;
    int rowBase = blockIdx.x * 128;
    int lane = t & 63;
    int wv   = t >> 6;
    int wr   = wv >> 1, wc = wv & 1;
    int ml   = lane & 15, quad = lane >> 4;
    int srow0 = wv * 32 + (lane >> 2);
    int cchunk = lane & 3;

    f32x4 acc[4][4];
#pragma unroll
    for (int i = 0; i < 4; ++i)
#pragma unroll
        for (int j = 0; j < 4; ++j) acc[i][j] = (f32x4){0.f, 0.f, 0.f, 0.f};

    // ---- phase 1: K=64, A = ax, B = Wt1 ----
    for (int kt = 0; kt < 64; kt += 32) {
        __syncthreads();
#pragma unroll
        for (int inst = 0; inst < 2; ++inst) {
            int r  = srow0 + inst * 16;
            int gc = (cchunk ^ (r & 3)) * 8;
            int gr = rowBase + r; if (gr >= n) gr = n - 1;
            load_lds16(A + (size_t)gr * 64 + kt + gc,
                       &As[(wv * 128 + inst * 64) * 8]);
            load_lds16(Wt1 + (size_t)r * 64 + kt + gc,
                       &Bs[(wv * 128 + inst * 64) * 8]);
        }
        __syncthreads();
        bf16x8 af[4], bfv[4];
#pragma unroll
        for (int i = 0; i < 4; ++i) {
            int ra = wr * 64 + i * 16 + ml;
            int rb = wc * 64 + i * 16 + ml;
            af[i]  = *(const bf16x8*)&As[(ra * 4 + (quad ^ (ra & 3))) * 8];
            bfv[i] = *(const bf16x8*)&Bs[(rb * 4 + (quad ^ (rb & 3))) * 8];
        }
#pragma unroll
        for (int i = 0; i < 4; ++i)
#pragma unroll
            for (int j = 0; j < 4; ++j)
                acc[i][j] = __builtin_amdgcn_mfma_f32_16x16x32_bf16(
                    af[i], bfv[j], acc[i][j], 0, 0, 0);
    }
    __syncthreads();   // As/Bs reads done in ALL threads before H1 overwrites As

    // ---- epilogue 1: +b1, write hcat[:,0:128] and H1 (swizzled bf16) ----
    {
        float b4[4];
#pragma unroll
        for (int j = 0; j < 4; ++j) b4[j] = b1[wc * 64 + j * 16 + ml];
#pragma unroll
        for (int i = 0; i < 4; ++i) {
#pragma unroll
            for (int reg = 0; reg < 4; ++reg) {
                int r  = wr * 64 + i * 16 + quad * 4 + reg;
                int gr = rowBase + r;
#pragma unroll
                for (int j = 0; j < 4; ++j) {
                    int c  = wc * 64 + j * 16 + ml;
                    bf16 bv = (bf16)(acc[i][j][reg] + b4[j]);
                    int kt2 = c >> 5, cc = c & 31;
                    H1[kt2 * 4096 + (r * 4 + ((cc >> 3) ^ (r & 3))) * 8 + (cc & 7)] = bv;
                    if (gr < n) hcat[(size_t)gr * 384 + c] = bv;
                }
            }
        }
    }

#pragma unroll
    for (int i = 0; i < 4; ++i)
#pragma unroll
        for (int j = 0; j < 4; ++j) acc[i][j] = (f32x4){0.f, 0.f, 0.f, 0.f};

    // ---- phase 2: K=128, A = H1 (LDS-resident), B = Wt2 ----
    for (int kt = 0; kt < 4; ++kt) {
        __syncthreads();
#pragma unroll
        for (int inst = 0; inst < 2; ++inst) {
            int r  = srow0 + inst * 16;
            int gc = (cchunk ^ (r & 3)) * 8;
            load_lds16(Wt2 + (size_t)r * 128 + kt * 32 + gc,
                       &Bs[(wv * 128 + inst * 64) * 8]);
        }
        __syncthreads();
        bf16x8 af[4], bfv[4];
#pragma unroll
        for (int i = 0; i < 4; ++i) {
            int ra = wr * 64 + i * 16 + ml;
            int rb = wc * 64 + i * 16 + ml;
            af[i]  = *(const bf16x8*)&H1[kt * 4096 + (ra * 4 + (quad ^ (ra & 3))) * 8];
            bfv[i] = *(const bf16x8*)&Bs[(rb * 4 + (quad ^ (rb & 3))) * 8];
        }
#pragma unroll
        for (int i = 0; i < 4; ++i)
#pragma unroll
            for (int j = 0; j < 4; ++j)
                acc[i][j] = __builtin_amdgcn_mfma_f32_16x16x32_bf16(
                    af[i], bfv[j], acc[i][j], 0, 0, 0);
    }

    // ---- epilogue 2: xw8 = fp8(dinv[row] * acc) ----
#pragma unroll
    for (int i = 0; i < 4; ++i) {
#pragma unroll
        for (int reg = 0; reg < 4; ++reg) {
            int gr = rowBase + wr * 64 + i * 16 + quad * 4 + reg;
            if (gr < n) {
                float sc = dinv[gr];
#pragma unroll
                for (int j = 0; j < 4; ++j) {
                    int c = wc * 64 + j * 16 + ml;
                    xw8[(size_t)gr * 128 + c] =
                        convert_out(acc[i][j][reg] * sc, (fp8s*)nullptr);
                }
            }
        }
    }
}

// ---------------- fused MLP head (k-tile-stationary, BM=128, all 3 slabs) --------
// 128 rows/block, grid (N+127)/128. Per 32-K step: stage one A tile (8KB) +
// all three lW1 slab tiles (3x8KB); accumulate acc[3][4][4] (~224 VGPR,
// launch_bounds(256,2)). hcat read ONCE; 48 MFMA per barrier.
__launch_bounds__(256, 2)
__global__ void head_gemm(const bf16* __restrict__ A, const bf16* __restrict__ Bt,
                          const float* __restrict__ lb1, const float* __restrict__ lW2,
                          const float* __restrict__ lb2,
                          float* __restrict__ out, int n) {
    __shared__ bf16 As[128 * 32];
    __shared__ bf16 Bs[3][128 * 32];
    __shared__ float plds[2][128][2];
    int t = threadIdx.x;
    int rowBase = blockIdx.x * 128;
    int lane = t & 63;
    int wv   = t >> 6;
    int wr   = wv >> 1, wc = wv & 1;
    int ml   = lane & 15, quad = lane >> 4;
    int srow0 = wv * 32 + (lane >> 2);          // 128 rows over 4 waves x 2 insts
    int cchunk = lane & 3;

    f32x4 acc[3][4][4];
#pragma unroll
    for (int s = 0; s < 3; ++s)
#pragma unroll
        for (int i = 0; i < 4; ++i)
#pragma unroll
            for (int j = 0; j < 4; ++j) acc[s][i][j] = (f32x4){0.f, 0.f, 0.f, 0.f};

    for (int kt = 0; kt < 384; kt += 32) {
        __syncthreads();
#pragma unroll
        for (int inst = 0; inst < 2; ++inst) {
            int r  = srow0 + inst * 16;
            int gc = (cchunk ^ (r & 3)) * 8;
            int gr = rowBase + r; if (gr >= n) gr = n - 1;
            load_lds16(A + (size_t)gr * 384 + kt + gc,
                       &As[(wv * 128 + inst * 64) * 8]);
#pragma unroll
            for (int s = 0; s < 3; ++s)
                load_lds16(Bt + (size_t)(s * 128 + r) * 384 + kt + gc,
                           &Bs[s][(wv * 128 + inst * 64) * 8]);
        }
        __syncthreads();
        bf16x8 af[4];
#pragma unroll
        for (int i = 0; i < 4; ++i) {
            int ra = wr * 64 + i * 16 + ml;
            af[i] = *(const bf16x8*)&As[(ra * 4 + (quad ^ (ra & 3))) * 8];
        }
#pragma unroll
        for (int s = 0; s < 3; ++s)
#pragma unroll
            for (int j = 0; j < 4; ++j) {
                int rb = wc * 64 + j * 16 + ml;
                bf16x8 bv = *(const bf16x8*)&Bs[s][(rb * 4 + (quad ^ (rb & 3))) * 8];
#pragma unroll
                for (int i = 0; i < 4; ++i)
                    acc[s][i][j] = __builtin_amdgcn_mfma_f32_16x16x32_bf16(
                        af[i], bv, acc[s][i][j], 0, 0, 0);
            }
    }

    // epilogue: relu(+lb1) @ lW2^T, summed over slabs+cols in-register
    float b4[3][4], w0[3][4], w1[3][4];
#pragma unroll
    for (int s = 0; s < 3; ++s)
#pragma unroll
        for (int j = 0; j < 4; ++j) {
            int gc = s * 128 + wc * 64 + j * 16 + ml;
            b4[s][j] = lb1[gc];
            w0[s][j] = lW2[gc];
            w1[s][j] = lW2[384 + gc];
        }
#pragma unroll
    for (int i = 0; i < 4; ++i) {
#pragma unroll
        for (int reg = 0; reg < 4; ++reg) {
            float p0 = 0.f, p1 = 0.f;
#pragma unroll
            for (int s = 0; s < 3; ++s)
#pragma unroll
                for (int j = 0; j < 4; ++j) {
                    float v = fmaxf(acc[s][i][j][reg] + b4[s][j], 0.f);
                    p0 += v * w0[s][j];
                    p1 += v * w1[s][j];
                }
#pragma unroll
            for (int m = 1; m < 16; m <<= 1) {
                p0 += __shfl_xor(p0, m, 64);
                p1 += __shfl_xor(p1, m, 64);
            }
            if (ml == 0) {
                int rl = wr * 64 + i * 16 + quad * 4 + reg;
                plds[wc][rl][0] = p0;           // unique writer per (wc,rl)
                plds[wc][rl][1] = p1;
            }
        }
    }

    __syncthreads();
    if (t < 128) {
        int gr = rowBase + t;
        if (gr < n) {
            float l0 = plds[0][t][0] + plds[1][t][0] + lb2[0];
            float l1 = plds[0][t][1] + plds[1][t][1] + lb2[1];
            size_t seg = (size_t)n * 2;
            *(float2*)(out + (size_t)gr * 2) = make_float2(l0, l1);
            float m  = fmaxf(l0, l1);
            float e0 = expf(l0 - m), e1 = expf(l1 - m);
            float inv = 1.f / (e0 + e1);
            *(float2*)(out + seg + (size_t)gr * 2) = make_float2(e0 * inv, e1 * inv);
        }
    }
}

// ---------------- aggregation (slice-owned, 8 lanes/node, x4 unroll) ------------
// 8 lanes per node; lane owns a 16B slice of the row and accumulates it
// over all edges serially. col[j] broadcast within the group. No shuffles.
// x4 unroll: 4 independent 128B row-gathers in flight per lane.

// 64-dim bf16 rows (128B): lane covers cols [sub*8, +8).
__launch_bounds__(256)
__global__ void aggregate64(const bf16* __restrict__ xs, const int* __restrict__ rpS,
                            const int* __restrict__ rpE,
                            const int* __restrict__ col, const float* __restrict__ dinv,
                            bf16* __restrict__ out, int n) {
    int gid = blockIdx.x * 256 + threadIdx.x;
    int v   = gid >> 3;
    int sub = gid & 7;
    if (v >= n) return;
    float di = dinv[v];
    int b = rpS[v], e = rpE[v];
    const bf16* base = xs + sub * 8;
    float acc[8] = {0.f, 0.f, 0.f, 0.f, 0.f, 0.f, 0.f, 0.f};
    int j = b;
    for (; j + 4 <= e; j += 4) {
        int s0 = col[j], s1 = col[j + 1], s2 = col[j + 2], s3 = col[j + 3];
        bf16x8 m0 = *(const bf16x8*)(base + (size_t)s0 * 64);
        bf16x8 m1 = *(const bf16x8*)(base + (size_t)s1 * 64);
        bf16x8 m2 = *(const bf16x8*)(base + (size_t)s2 * 64);
        bf16x8 m3 = *(const bf16x8*)(base + (size_t)s3 * 64);
#pragma unroll
        for (int k = 0; k < 8; ++k)
            acc[k] += ((float)m0[k] + (float)m1[k]) + ((float)m2[k] + (float)m3[k]);
    }
    for (; j < e; ++j) {
        int s = col[j];
        bf16x8 m = *(const bf16x8*)(base + (size_t)s * 64);
#pragma unroll
        for (int k = 0; k < 8; ++k) acc[k] += (float)m[k];
    }
    bf16x8 mv = *(const bf16x8*)(base + (size_t)v * 64);
    bf16x8 o;
#pragma unroll
    for (int k = 0; k < 8; ++k) o[k] = (bf16)(di * (acc[k] + (float)mv[k]));
    *(bf16x8*)(out + (size_t)v * 64 + sub * 8) = o;
}

// 128-dim fp8 rows (128B): lane covers cols [sub*16, +16).
__launch_bounds__(256)
__global__ void aggregate_fp8(const fp8s* __restrict__ xs, const int* __restrict__ rpS,
                              const int* __restrict__ rpE,
                              const int* __restrict__ col, const float* __restrict__ dinv,
                              const float* __restrict__ bias, bf16* __restrict__ out,
                              int outStride, int n) {
    int gid = blockIdx.x * 256 + threadIdx.x;
    int v   = gid >> 3;
    int sub = gid & 7;
    if (v >= n) return;
    float di = dinv[v];
    int b = rpS[v], e = rpE[v];
    const fp8s* base = xs + sub * 16;
    float acc[16];
#pragma unroll
    for (int k = 0; k < 16; ++k) acc[k] = 0.f;
    int j = b;
    for (; j + 4 <= e; j += 4) {
        int s0 = col[j], s1 = col[j + 1], s2 = col[j + 2], s3 = col[j + 3];
        uint4 p0 = *(const uint4*)(base + (size_t)s0 * 128);
        uint4 p1 = *(const uint4*)(base + (size_t)s1 * 128);
        uint4 p2 = *(const uint4*)(base + (size_t)s2 * 128);
        uint4 p3 = *(const uint4*)(base + (size_t)s3 * 128);
#pragma unroll
        for (int q = 0; q < 4; ++q) {
            unsigned w0 = (q == 0) ? p0.x : (q == 1) ? p0.y : (q == 2) ? p0.z : p0.w;
            unsigned w1 = (q == 0) ? p1.x : (q == 1) ? p1.y : (q == 2) ? p1.z : p1.w;
            unsigned w2 = (q == 0) ? p2.x : (q == 1) ? p2.y : (q == 2) ? p2.z : p2.w;
            unsigned w3 = (q == 0) ? p3.x : (q == 1) ? p3.y : (q == 2) ? p3.z : p3.w;
            float4 f0 = fp8x4_to_f4(w0), f1 = fp8x4_to_f4(w1);
            float4 f2 = fp8x4_to_f4(w2), f3 = fp8x4_to_f4(w3);
            acc[q * 4 + 0] += (f0.x + f1.x) + (f2.x + f3.x);
            acc[q * 4 + 1] += (f0.y + f1.y) + (f2.y + f3.y);
            acc[q * 4 + 2] += (f0.z + f1.z) + (f2.z + f3.z);
            acc[q * 4 + 3] += (f0.w + f1.w) + (f2.w + f3.w);
        }
    }
    for (; j < e; ++j) {
        int s = col[j];
        uint4 p = *(const uint4*)(base + (size_t)s * 128);
        float4 f0 = fp8x4_to_f4(p.x), f1 = fp8x4_to_f4(p.y),
               f2 = fp8x4_to_f4(p.z), f3 = fp8x4_to_f4(p.w);
        acc[0]  += f0.x; acc[1]  += f0.y; acc[2]  += f0.z; acc[3]  += f0.w;
        acc[4]  += f1.x; acc[5]  += f1.y; acc[6]  += f1.z; acc[7]  += f1.w;
        acc[8]  += f2.x; acc[9]  += f2.y; acc[10] += f2.z; acc[11] += f2.w;
        acc[12] += f3.x; acc[13] += f3.y; acc[14] += f3.z; acc[15] += f3.w;
    }
    uint4 pv = *(const uint4*)(base + (size_t)v * 128);
    float4 f0 = fp8x4_to_f4(pv.x), f1 = fp8x4_to_f4(pv.y),
           f2 = fp8x4_to_f4(pv.z), f3 = fp8x4_to_f4(pv.w);
    float fv[16] = {f0.x, f0.y, f0.z, f0.w, f1.x, f1.y, f1.z, f1.w,
                    f2.x, f2.y, f2.z, f2.w, f3.x, f3.y, f3.z, f3.w};
    const float* bb = bias + sub * 16;
    bf16x8 o0, o1;
#pragma unroll
    for (int k = 0; k < 8; ++k)
        o0[k] = (bf16)(di * (acc[k] + fv[k]) + bb[k]);
#pragma unroll
    for (int k = 0; k < 8; ++k)
        o1[k] = (bf16)(di * (acc[8 + k] + fv[8 + k]) + bb[8 + k]);
    bf16* op = out + (size_t)v * outStride + sub * 16;
    *(bf16x8*)op = o0;
    *(bf16x8*)(op + 8) = o1;
}

extern "C" void kernel_launch(void* const* d_in, const int* in_sizes, int n_in,
                              void* d_out, int out_size, void* d_ws, size_t ws_size,
                              hipStream_t stream) {
    const float* x   = (const float*)d_in[0];
    const int*   ei  = (const int*)d_in[1];
    const float* W1  = (const float*)d_in[2];
    const float* b1  = (const float*)d_in[3];
    const float* W2  = (const float*)d_in[4];
    const float* b2  = (const float*)d_in[5];
    const float* W3  = (const float*)d_in[6];
    const float* b3  = (const float*)d_in[7];
    const float* lW1 = (const float*)d_in[8];
    const float* lb1 = (const float*)d_in[9];
    const float* lW2 = (const float*)d_in[10];
    const float* lb2 = (const float*)d_in[11];
    float* out = (float*)d_out;

    int N = in_sizes[0] / 64;
    int E = in_sizes[1] / 2;
    const int* src = ei;
    const int* dst = ei + E;

    char* ws = (char*)d_ws;
    size_t off = 0;
    auto take = [&](size_t bytes) -> char* {
        char* p = ws + off;
        off += (bytes + 255) & ~(size_t)255;
        return p;
    };
    int nBlk  = (N + 255) / 256;
    int nbuck = nBlk;
    int*   cnt    = (int*)take((size_t)N * 4);         // fallback only
    int*   fill   = (int*)take((size_t)N * 4);         // fallback only
    int*   rpS    = (int*)take((size_t)N * 4);
    int*   rpE    = (int*)take((size_t)N * 4);
    float* dinv   = (float*)take((size_t)N * 4);
    int*   bsum   = (int*)take((size_t)nBlk * 4);      // fallback only
    int*   gcount = (int*)take((size_t)nbuck * 4);
    size_t regionE = (nbuck <= 256 && N <= 65536)
                   ? (size_t)nbuck * BUCKET_CAP : (size_t)E;
    int*   col    = (int*)take(regionE * 4);
    unsigned int* pairs = (unsigned int*)take(regionE * 4);
    bf16*  xs0    = (bf16*)take((size_t)N * 64 * 2);
    bf16*  ax     = (bf16*)take((size_t)N * 64 * 2);
    bf16*  Wt1    = (bf16*)take((size_t)64 * 128 * 2);
    bf16*  Wt2    = (bf16*)take((size_t)128 * 128 * 2);
    bf16*  Wt3    = (bf16*)take((size_t)128 * 128 * 2);
    bf16*  lW1_bf = (bf16*)take((size_t)384 * 384 * 2);
    fp8s*  xw8    = (fp8s*)take((size_t)N * 128);
    bf16*  hcat   = (bf16*)take((size_t)N * 384 * 2);

    // CSR build + prep (3 dispatches: memset + bin_prep(+weights) + fill)
    if (nbuck <= 256 && N <= 65536) {
        hipMemsetAsync(gcount, 0, (size_t)nbuck * 4, stream);
        bin_prep<<<nbuck + 736, 256, 0, stream>>>(
            src, dst, gcount, pairs, E, nbuck,
            W1, W2, W3, lW1, Wt1, Wt2, Wt3, lW1_bf);
        csr_fill_full<<<nbuck, 256, 0, stream>>>(
            pairs, gcount, x, rpS, rpE, dinv, col, xs0, N);
    } else {
        bin_prep<<<736, 256, 0, stream>>>(                 // weights only
            src, dst, gcount, pairs, 0, 0,
            W1, W2, W3, lW1, Wt1, Wt2, Wt3, lW1_bf);
        init_kernel<<<nBlk, 256, 0, stream>>>(cnt, fill, N);
        hist_kernel<<<(E + 255) / 256, 256, 0, stream>>>(dst, cnt, E);
        block_reduce<<<nBlk, 256, 0, stream>>>(cnt, bsum, N);
        scan_bsums<<<1, 256, 0, stream>>>(bsum, nBlk);
        write_rp_fb<<<nBlk, 256, 0, stream>>>(cnt, bsum, x, rpS, rpE, dinv, xs0, N);
        fill_kernel<<<(E + 255) / 256, 256, 0, stream>>>(src, dst, rpS, fill, col, E);
    }

    int gemmBlocks = (N + 127) / 128;
    int aggBlocks  = (N + 31) / 32;

    // conv1+conv2: aggregate (64-dim bf16), then fused GEMM pair
    //   h1 = ax@Wt1+b1 -> hcat[:,0:128];  xw8 = fp8(dinv * h1@Wt2)
    aggregate64<<<aggBlocks, 256, 0, stream>>>(xs0, rpS, rpE, col, dinv, ax, N);
    conv12_gemm<<<gemmBlocks, 256, 0, stream>>>(
        ax, Wt1, b1, Wt2, dinv, hcat, xw8, N);
    // conv2 aggregate (+b2), conv3 GEMM, conv3 aggregate (+b3)
    aggregate_fp8<<<aggBlocks, 256, 0, stream>>>(xw8, rpS, rpE, col, dinv, b2, hcat + 128, 384, N);
    mfma_gemm<0, fp8s><<<dim3(gemmBlocks, 1), 256, 0, stream>>>(
        hcat + 128, 384, 128, Wt3, nullptr, dinv, xw8, 128, N);
    aggregate_fp8<<<aggBlocks, 256, 0, stream>>>(xw8, rpS, rpE, col, dinv, b3, hcat + 256, 384, N);

    // fused MLP head: BM=128 k-tile-stationary, hcat read once, softmax in-block
    head_gemm<<<gemmBlocks, 256, 0, stream>>>(hcat, lW1_bf, lb1, lW2, lb2, out, N);
}